// Round 2
// baseline (19958.055 us; speedup 1.0000x reference)
//
#include <hip/hip_runtime.h>

// ---- problem dims ----
#define Bn   256
#define Tn   512
#define Fn   5
#define Hn   512
#define BBn  128
#define KSn  544          // 512 (H) + 5 (x) + padding to 17*32
#define NC   8            // clusters (one per XCD by blockIdx%8 round-robin)
#define WPC  32           // workgroups per cluster
#define NWG  (NC*WPC)

typedef __attribute__((ext_vector_type(8))) short bf16x8;
typedef __attribute__((ext_vector_type(4))) float f32x4;

// ---- d_ws layout (bytes) ----
#define WS_BAR   0                        // 8 counters, 128B apart -> needs 1024B (was 256: counters 2..7
                                          // overlapped h_shared and were clobbered every step -> deadlock)
#define WS_H     1024                     // h_shared   [Bn][KSn] bf16 (cols 512..516 = x_t, rest pad 0)
#define WS_HL    (WS_H   + Bn*KSn*2)      // hlstm      [Bn][KSn] bf16
#define WS_FEAT  (WS_HL  + Bn*KSn*2)      // feat       [Bn][BBn] bf16
#define WS_WH    (WS_FEAT + Bn*BBn*2)     // Wh_ext     [2048][KSn] bf16  (k>=512 -> Wi, pad 0)
#define WS_BB    (WS_WH  + 2048*KSn*2)    // bb_ext     [128][KSn] bf16   (k>=512 -> x-part)
#define WS_FF    (WS_BB  + 128*KSn*2)     // ff weights [4][Hn][BBn] bf16 (ff1,ff2,ta,tb)
#define WS_END   (WS_FF  + 4*Hn*BBn*2)

// ---- d_out layout (floats) ----
#define YO 0                  // y_pred [Bn][Tn][2]
#define EO (Bn*Tn*2)          // e_pred [Bn][Tn]
#define HO (EO + Bn*Tn)       // h_last [Bn][Hn]
#define CO (HO + Bn*Hn)       // c_last [Bn][Hn]

__device__ __forceinline__ unsigned short f2bf(float f) {
  union { float f; unsigned u; } v; v.f = f;
  unsigned r = v.u + 0x7FFFu + ((v.u >> 16) & 1u);
  return (unsigned short)(r >> 16);
}
__device__ __forceinline__ float bf2f(unsigned short u) {
  union { unsigned u; float f; } v; v.u = ((unsigned)u) << 16;
  return v.f;
}
__device__ __forceinline__ float sigm(float x) { return 1.f / (1.f + __expf(-x)); }
__device__ __forceinline__ float tanhx(float x) {
  float e = __expf(2.f * x);
  return 1.f - 2.f / (e + 1.f);
}

// ---------------- weight prep: f32 -> bf16, padded/extended layouts ----------------
__global__ void __launch_bounds__(256) prep_weights(
    const float* __restrict__ Wh, const float* __restrict__ Wi, const float* __restrict__ bbW,
    const float* __restrict__ f1W, const float* __restrict__ f2W,
    const float* __restrict__ taW, const float* __restrict__ tbW, char* __restrict__ ws)
{
  unsigned short* wh = (unsigned short*)(ws + WS_WH);
  unsigned short* bb = (unsigned short*)(ws + WS_BB);
  unsigned short* ff = (unsigned short*)(ws + WS_FF);
  const int n1 = 2048 * KSn, n2 = 128 * KSn, n3 = Hn * BBn;
  const int ntot = n1 + n2 + 4 * n3;
  for (int i = blockIdx.x * blockDim.x + threadIdx.x; i < ntot; i += gridDim.x * blockDim.x) {
    if (i < n1) {
      int c = i / KSn, k = i % KSn;
      float v = (k < 512) ? Wh[c * 512 + k] : ((k < 517) ? Wi[c * 5 + (k - 512)] : 0.f);
      wh[i] = f2bf(v);
    } else if (i < n1 + n2) {
      int j = i - n1; int o = j / KSn, k = j % KSn;
      float v = (k < 512) ? bbW[o * 517 + 5 + k] : ((k < 517) ? bbW[o * 517 + (k - 512)] : 0.f);
      bb[j] = f2bf(v);
    } else {
      int j = i - n1 - n2; int m = j / n3; int r = j % n3;
      const float* src = (m == 0) ? f1W : (m == 1) ? f2W : (m == 2) ? taW : tbW;
      ff[j] = f2bf(src[r]);
    }
  }
}

// ---------------- cluster barrier ----------------
// release: __syncthreads drains all waves' stores; tid0 __threadfence (wbl2) pushes to coherence point.
// acquire: tid0 spins on agent-scope atomic load (sc1 -> bypasses stale L2); __threadfence (buffer_inv)
// invalidates L1/L2; trailing s_barrier orders other waves' loads after the invalidate.
// Watchdog: bounded spin so any residual hang degrades to a wrong answer (diagnosable) instead of timeout.
__device__ __forceinline__ void cluster_barrier(int* ctr, int target) {
  __syncthreads();
  if (threadIdx.x == 0) {
    __threadfence();
    atomicAdd(ctr, 1);
    int tries = 0;
    while (__hip_atomic_load(ctr, __ATOMIC_RELAXED, __HIP_MEMORY_SCOPE_AGENT) < target) {
      __builtin_amdgcn_s_sleep(2);
      if (++tries >= (1 << 18)) break;   // ~tens of ms; never triggers in a healthy run
    }
    __threadfence();
  }
  __syncthreads();
}

// ---------------- main persistent scan kernel ----------------
__global__ void __launch_bounds__(256, 1) ebl_main(
    const float* __restrict__ x,   const float* __restrict__ bi,
    const float* __restrict__ bbb, const float* __restrict__ f1b, const float* __restrict__ f2b,
    const float* __restrict__ tab, const float* __restrict__ tbb,
    const float* __restrict__ predW, const float* __restrict__ predb,
    const float* __restrict__ enW,   const float* __restrict__ enb,
    float* __restrict__ out, char* __restrict__ ws)
{
  int* bar = (int*)(ws + WS_BAR);
  unsigned short* hsh = (unsigned short*)(ws + WS_H);
  unsigned short* hls = (unsigned short*)(ws + WS_HL);
  unsigned short* fsh = (unsigned short*)(ws + WS_FEAT);
  const unsigned short* wh  = (const unsigned short*)(ws + WS_WH);
  const unsigned short* bbw = (const unsigned short*)(ws + WS_BB);
  const unsigned short* ffw = (const unsigned short*)(ws + WS_FF);

  const int tid  = threadIdx.x;
  const int lane = tid & 63;
  const int wv   = tid >> 6;              // wave 0..3 = gate / ff-matrix index
  const int cl   = blockIdx.x & 7;        // cluster (XCD round-robin)
  const int wg   = blockIdx.x >> 3;       // 0..31 within cluster
  const int rbase = cl * WPC;             // batch-row base of cluster (32 rows)
  const int jbase = wg * 16;              // hidden-column slice of this WG

  __shared__ float lbuf[4][16][36];       // [gate/matrix][col][row(padded)] f32

  int* ctr = bar + cl * 32;               // 128B apart per cluster (region is 1024B)
  int phase = 0;

  const int l15 = lane & 15;
  const int l4  = lane >> 4;
  const int cc  = tid & 15;               // combine-phase column
  const int rr  = tid >> 4;               // combine-phase row (0..15; also rr+16)

  // ---- stationary per-thread preloads ----
  float hp0[8], hp1[8], hpe[8];
  if (wv == 0) {
    #pragma unroll
    for (int j = 0; j < 8; ++j) {
      hp0[j] = predW[lane * 8 + j];
      hp1[j] = predW[512 + lane * 8 + j];
      hpe[j] = enW[lane * 8 + j];
    }
  }
  float biC[4];
  #pragma unroll
  for (int g = 0; g < 4; ++g) biC[g] = bi[g * 512 + jbase + cc];
  const float fb1 = f1b[jbase + cc], fb2v = f2b[jbase + cc];
  const float fta = tab[jbase + cc], ftb = tbb[jbase + cc];
  const float bbB = (wg < 8) ? bbb[wg * 16 + l15] : 0.f;

  float cst0 = 0.f, cst1 = 0.f;           // LSTM c-state: rows (rbase+rr, rbase+rr+16), col jbase+cc

  // ---- prologue: x_0 into h_shared ext cols ----
  if (tid < Fn) {
    int b = rbase + wg;
    hsh[b * KSn + 512 + tid] = f2bf(x[(b * Tn + 0) * Fn + tid]);
  }
  ++phase; cluster_barrier(ctr, phase * WPC);

  for (int t = 0; t < Tn; ++t) {
    // ---------- stage A: z = [h,x_t] @ Wh_ext^T ; gates ; h_lstm ----------
    // fused heads for step t-1 (wave 0; h_shared currently holds h_{t-1})
    if (wv == 0 && t > 0) {
      const int b = rbase + wg;
      const unsigned short* hrow = hsh + b * KSn + lane * 8;
      float s0 = 0.f, s1 = 0.f, se = 0.f;
      #pragma unroll
      for (int j = 0; j < 8; ++j) {
        float hv = bf2f(hrow[j]);
        s0 += hv * hp0[j]; s1 += hv * hp1[j]; se += hv * hpe[j];
      }
      #pragma unroll
      for (int off = 32; off > 0; off >>= 1) {
        s0 += __shfl_down(s0, off);
        s1 += __shfl_down(s1, off);
        se += __shfl_down(se, off);
      }
      if (lane == 0) {
        out[YO + b * (Tn * 2) + (t - 1) * 2 + 0] = s0 + predb[0];
        out[YO + b * (Tn * 2) + (t - 1) * 2 + 1] = s1 + predb[1];
        out[EO + b * Tn + (t - 1)]               = se + enb[0];
      }
    }
    // x_t into hlstm ext cols (consumed by stage B after barrier 1)
    if (tid < Fn) {
      int b = rbase + wg;
      hls[b * KSn + 512 + tid] = f2bf(x[(b * Tn + t) * Fn + tid]);
    }

    {
      f32x4 acc0 = {0.f, 0.f, 0.f, 0.f}, acc1 = {0.f, 0.f, 0.f, 0.f};
      const unsigned short* arow0 = hsh + (rbase + l15) * KSn + l4 * 8;
      const unsigned short* arow1 = hsh + (rbase + 16 + l15) * KSn + l4 * 8;
      const unsigned short* brow  = wh + (wv * 512 + jbase + l15) * KSn + l4 * 8;
      #pragma unroll
      for (int ks = 0; ks < 17; ++ks) {
        bf16x8 a0 = *(const bf16x8*)(arow0 + ks * 32);
        bf16x8 a1 = *(const bf16x8*)(arow1 + ks * 32);
        bf16x8 b8 = *(const bf16x8*)(brow + ks * 32);
        acc0 = __builtin_amdgcn_mfma_f32_16x16x32_bf16(a0, b8, acc0, 0, 0, 0);
        acc1 = __builtin_amdgcn_mfma_f32_16x16x32_bf16(a1, b8, acc1, 0, 0, 0);
      }
      *(f32x4*)(&lbuf[wv][l15][l4 * 4])      = acc0;   // rows l4*4..+3
      *(f32x4*)(&lbuf[wv][l15][16 + l4 * 4]) = acc1;
    }
    __syncthreads();
    {
      float zi0 = lbuf[0][cc][rr]      + biC[0];
      float zg0 = lbuf[1][cc][rr]      + biC[1];
      float zf0 = lbuf[2][cc][rr]      + biC[2];
      float zo0 = lbuf[3][cc][rr]      + biC[3];
      float zi1 = lbuf[0][cc][rr + 16] + biC[0];
      float zg1 = lbuf[1][cc][rr + 16] + biC[1];
      float zf1 = lbuf[2][cc][rr + 16] + biC[2];
      float zo1 = lbuf[3][cc][rr + 16] + biC[3];
      float cn0 = cst0 * sigm(zf0 + 1.f) + tanhx(zi0) * sigm(zg0);
      float cn1 = cst1 * sigm(zf1 + 1.f) + tanhx(zi1) * sigm(zg1);
      float hl0 = tanhx(cn0) * sigm(zo0);
      float hl1 = tanhx(cn1) * sigm(zo1);
      cst0 = cn0; cst1 = cn1;
      const int b0 = rbase + rr, b1 = rbase + rr + 16;
      hls[b0 * KSn + jbase + cc] = f2bf(hl0);
      hls[b1 * KSn + jbase + cc] = f2bf(hl1);
      if (t == Tn - 1) {
        out[CO + b0 * Hn + jbase + cc] = cn0;
        out[CO + b1 * Hn + jbase + cc] = cn1;
      }
    }
    ++phase; cluster_barrier(ctr, phase * WPC);

    // ---------- stage B: feat = lecun_tanh([h_lstm,x_t] @ bb_ext^T) ----------
    if (wg < 8 && wv < 2) {
      f32x4 accB = {0.f, 0.f, 0.f, 0.f};
      const unsigned short* arow = hls + (rbase + wv * 16 + l15) * KSn + l4 * 8;
      const unsigned short* brow = bbw + (wg * 16 + l15) * KSn + l4 * 8;
      #pragma unroll
      for (int ks = 0; ks < 17; ++ks) {
        bf16x8 a = *(const bf16x8*)(arow + ks * 32);
        bf16x8 b8 = *(const bf16x8*)(brow + ks * 32);
        accB = __builtin_amdgcn_mfma_f32_16x16x32_bf16(a, b8, accB, 0, 0, 0);
      }
      #pragma unroll
      for (int j = 0; j < 4; ++j) {
        float v = accB[j] + bbB;
        v = 1.7159f * tanhx(0.666f * v);
        int b = rbase + wv * 16 + l4 * 4 + j;
        fsh[b * BBn + wg * 16 + l15] = f2bf(v);
      }
    }
    ++phase; cluster_barrier(ctr, phase * WPC);

    // ---------- stage C: ff1/ff2/ta/tb (wave = matrix), h_new ----------
    {
      f32x4 ac0 = {0.f, 0.f, 0.f, 0.f}, ac1 = {0.f, 0.f, 0.f, 0.f};
      const unsigned short* arow0 = fsh + (rbase + l15) * BBn + l4 * 8;
      const unsigned short* arow1 = fsh + (rbase + 16 + l15) * BBn + l4 * 8;
      const unsigned short* brow  = ffw + wv * (Hn * BBn) + (jbase + l15) * BBn + l4 * 8;
      #pragma unroll
      for (int ks = 0; ks < 4; ++ks) {
        bf16x8 a0 = *(const bf16x8*)(arow0 + ks * 32);
        bf16x8 a1 = *(const bf16x8*)(arow1 + ks * 32);
        bf16x8 b8 = *(const bf16x8*)(brow + ks * 32);
        ac0 = __builtin_amdgcn_mfma_f32_16x16x32_bf16(a0, b8, ac0, 0, 0, 0);
        ac1 = __builtin_amdgcn_mfma_f32_16x16x32_bf16(a1, b8, ac1, 0, 0, 0);
      }
      *(f32x4*)(&lbuf[wv][l15][l4 * 4])      = ac0;
      *(f32x4*)(&lbuf[wv][l15][16 + l4 * 4]) = ac1;
    }
    __syncthreads();
    {
      float p10 = lbuf[0][cc][rr] + fb1,      p20 = lbuf[1][cc][rr] + fb2v;
      float pa0 = lbuf[2][cc][rr] + fta,      pb0 = lbuf[3][cc][rr] + ftb;
      float p11 = lbuf[0][cc][rr + 16] + fb1, p21 = lbuf[1][cc][rr + 16] + fb2v;
      float pa1 = lbuf[2][cc][rr + 16] + fta, pb1 = lbuf[3][cc][rr + 16] + ftb;
      float f10 = tanhx(p10), f20 = tanhx(p20), ti0 = sigm(pa0 + pb0);
      float f11 = tanhx(p11), f21 = tanhx(p21), ti1 = sigm(pa1 + pb1);
      float hn0 = f10 + ti0 * (f20 - f10);
      float hn1 = f11 + ti1 * (f21 - f11);
      const int b0 = rbase + rr, b1 = rbase + rr + 16;
      hsh[b0 * KSn + jbase + cc] = f2bf(hn0);
      hsh[b1 * KSn + jbase + cc] = f2bf(hn1);
      if (t == Tn - 1) {
        out[HO + b0 * Hn + jbase + cc] = hn0;
        out[HO + b1 * Hn + jbase + cc] = hn1;
      }
    }
    // x_{t+1} into h_shared ext cols (consumed by next stage A)
    if (t + 1 < Tn && tid < Fn) {
      int b = rbase + wg;
      hsh[b * KSn + 512 + tid] = f2bf(x[(b * Tn + t + 1) * Fn + tid]);
    }
    ++phase; cluster_barrier(ctr, phase * WPC);
  }

  // ---------- epilogue heads for t = Tn-1 ----------
  if (wv == 0) {
    const int b = rbase + wg;
    const unsigned short* hrow = hsh + b * KSn + lane * 8;
    float s0 = 0.f, s1 = 0.f, se = 0.f;
    #pragma unroll
    for (int j = 0; j < 8; ++j) {
      float hv = bf2f(hrow[j]);
      s0 += hv * hp0[j]; s1 += hv * hp1[j]; se += hv * hpe[j];
    }
    #pragma unroll
    for (int off = 32; off > 0; off >>= 1) {
      s0 += __shfl_down(s0, off);
      s1 += __shfl_down(s1, off);
      se += __shfl_down(se, off);
    }
    if (lane == 0) {
      out[YO + b * (Tn * 2) + (Tn - 1) * 2 + 0] = s0 + predb[0];
      out[YO + b * (Tn * 2) + (Tn - 1) * 2 + 1] = s1 + predb[1];
      out[EO + b * Tn + (Tn - 1)]               = se + enb[0];
    }
  }
}

extern "C" void kernel_launch(void* const* d_in, const int* in_sizes, int n_in,
                              void* d_out, int out_size, void* d_ws, size_t ws_size,
                              hipStream_t stream) {
  const float* x   = (const float*)d_in[0];
  const float* Wi  = (const float*)d_in[1];
  const float* bi  = (const float*)d_in[2];
  const float* Wh  = (const float*)d_in[3];
  const float* bbW = (const float*)d_in[4];
  const float* bbb = (const float*)d_in[5];
  const float* f1W = (const float*)d_in[6];
  const float* f1b = (const float*)d_in[7];
  const float* f2W = (const float*)d_in[8];
  const float* f2b = (const float*)d_in[9];
  const float* taW = (const float*)d_in[10];
  const float* tab = (const float*)d_in[11];
  const float* tbW = (const float*)d_in[12];
  const float* tbb = (const float*)d_in[13];
  const float* pW  = (const float*)d_in[14];
  const float* pb  = (const float*)d_in[15];
  const float* eW  = (const float*)d_in[16];
  const float* eb  = (const float*)d_in[17];
  float* out = (float*)d_out;
  char* ws = (char*)d_ws;

  // zero barriers + h/hlstm/feat shared activation buffers (replayed every graph launch)
  hipMemsetAsync(ws, 0, WS_WH, stream);
  prep_weights<<<2048, 256, 0, stream>>>(Wh, Wi, bbW, f1W, f2W, taW, tbW, ws);

  void* args[] = { (void*)&x, (void*)&bi, (void*)&bbb, (void*)&f1b, (void*)&f2b,
                   (void*)&tab, (void*)&tbb, (void*)&pW, (void*)&pb, (void*)&eW,
                   (void*)&eb, (void*)&out, (void*)&ws };
  hipLaunchCooperativeKernel((const void*)ebl_main, dim3(NWG), dim3(256), args, 0, stream);
}